// Round 9
// baseline (126.136 us; speedup 1.0000x reference)
//
#include <hip/hip_runtime.h>
#include <hip/hip_bf16.h>
#include <math.h>

#define TOKENS 8192
#define D_REAL 768
#define D_HID  512
#define D_MODEL 4096

typedef __attribute__((ext_vector_type(8))) short bf16x8;   // 8 bf16 in 4 VGPRs
typedef __attribute__((ext_vector_type(4))) float f32x4;    // MFMA accumulator

// fp32 -> bf16, round-to-nearest-even
__device__ inline unsigned short f2bf(float f) {
    union { float f; unsigned u; } v; v.f = f;
    unsigned r = v.u + 0x7FFFu + ((v.u >> 16) & 1u);
    return (unsigned short)(r >> 16);
}
__device__ inline float bf2f(unsigned short h) {
    union { unsigned u; float f; } v; v.u = ((unsigned)h) << 16;
    return v.f;
}
__device__ inline bf16x8 cvt8(float4 a, float4 b) {
    bf16x8 r;
    r[0] = (short)f2bf(a.x); r[1] = (short)f2bf(a.y);
    r[2] = (short)f2bf(a.z); r[3] = (short)f2bf(a.w);
    r[4] = (short)f2bf(b.x); r[5] = (short)f2bf(b.y);
    r[6] = (short)f2bf(b.z); r[7] = (short)f2bf(b.w);
    return r;
}

// async global->LDS, 16B per lane. LDS dest = wave-uniform base + lane*16.
__device__ inline void gload_lds16(const void* g, void* lds_wave_base) {
    __builtin_amdgcn_global_load_lds(
        (const __attribute__((address_space(1))) unsigned*)g,
        (__attribute__((address_space(3))) unsigned*)lds_wave_base,
        16, 0, 0);
}

// compiler-fence + hw barrier (no implicit waitcnt drain, unlike __syncthreads)
__device__ inline void BAR() {
    asm volatile("" ::: "memory");
    __builtin_amdgcn_s_barrier();
    asm volatile("" ::: "memory");
}

// ---------------------------------------------------------------------------
// GEMM1 (+fused gather): Hb = bf16(real[ids]) * w1b^T, bf16 out.
// Tile 64x128, BK=32, 4 waves (2x2). A reg-staged from fp32 real rows
// (float4 x2 -> cvt -> ds_write_b128); B via global_load_lds from w1b.
// Grid (128,4) = 512 blocks.
// ---------------------------------------------------------------------------
__global__ __launch_bounds__(256)
void gemm1_mfma(const float* __restrict__ real, const int* __restrict__ ids,
                const unsigned short* __restrict__ B,
                unsigned short* __restrict__ C)
{
    constexpr int K = D_REAL, N = D_HID;
    __shared__ __align__(16) unsigned short As[64 * 32];    // 4 KB
    __shared__ __align__(16) unsigned short Bs[128 * 32];   // 8 KB
    __shared__ int sIds[64];

    const int tid = threadIdx.x;
    const int rowBase = blockIdx.x * 64;
    const int colBase = blockIdx.y * 128;

    if (tid < 64) sIds[tid] = ids[rowBase + tid];
    __syncthreads();

    const int srow = tid >> 2;           // 0..63
    const int scol = (tid & 3) * 8;      // k offset
    const float* gA = real + (size_t)sIds[srow] * K + scol;
    const unsigned short* gB = B + (size_t)(colBase + srow) * K + scol;
    unsigned short* lB = Bs + (tid >> 6) * 512;

    const int lane = tid & 63;
    const int wv   = tid >> 6;
    const int wm   = (wv >> 1) * 32;
    const int wn   = (wv & 1) * 64;
    const int frow = lane & 15;
    const int fk   = (lane >> 4) * 8;

    f32x4 acc[2][4];
    #pragma unroll
    for (int i = 0; i < 2; i++)
        #pragma unroll
        for (int j = 0; j < 4; j++) acc[i][j] = (f32x4)0.f;

    for (int k0 = 0; k0 < K; k0 += 32) {
        gload_lds16(gB + k0,                lB);
        gload_lds16(gB + k0 + (size_t)64*K, lB + 2048);
        const float4 a0 = *reinterpret_cast<const float4*>(gA + k0);
        const float4 a1 = *reinterpret_cast<const float4*>(gA + k0 + 4);
        *reinterpret_cast<bf16x8*>(&As[srow * 32 + scol]) = cvt8(a0, a1);
        __syncthreads();   // drains gloads + ds_write + a-loads

        bf16x8 af[2], bg[4];
        #pragma unroll
        for (int i = 0; i < 2; i++)
            af[i] = *reinterpret_cast<const bf16x8*>(&As[(wm + i*16 + frow) * 32 + fk]);
        #pragma unroll
        for (int j = 0; j < 4; j++)
            bg[j] = *reinterpret_cast<const bf16x8*>(&Bs[(wn + j*16 + frow) * 32 + fk]);

        #pragma unroll
        for (int i = 0; i < 2; i++)
            #pragma unroll
            for (int j = 0; j < 4; j++)
                acc[i][j] = __builtin_amdgcn_mfma_f32_16x16x32_bf16(af[i], bg[j], acc[i][j], 0, 0, 0);
        __syncthreads();
    }

    const int orow0 = wm + (lane >> 4) * 4;
    const int ocol0 = wn + frow;
    #pragma unroll
    for (int i = 0; i < 2; i++)
        #pragma unroll
        for (int r = 0; r < 4; r++) {
            unsigned short* dst = C + (size_t)(rowBase + orow0 + i*16 + r) * N + colBase + ocol0;
            #pragma unroll
            for (int j = 0; j < 4; j++)
                dst[j * 16] = f2bf(acc[i][j][r]);
        }
}

// ---------------------------------------------------------------------------
// GEMM2, 128x128 / BK=64 8-phase-style schedule, 2 blocks/CU:
//   out[8192][4096] = Hb * w2b^T + embed[ids], fp32 out.
// 512 thr = 8 waves (2Mx4N), wave = 64x32 = 4mf x 2nf frags, BK=64 (kk=2).
// LDS 64 KB: A[2][128][64] + B[2][128][64] bf16, both-sides XOR swizzle
// (inverse-swizzled gload source + swizzled ds_read).
// Per K-tile, 2 phases:
//  p0: read af(mf0,1)+bg; STAGE(kt+1.B -> buf^1); BAR; MFMA; BAR
//  p1: read af(mf2,3); BAR(all A reads done); STAGE(kt+2.A -> buf);
//      MFMA; counted vmcnt; BAR
// vmcnt(2) at boundaries (kt+2.A may stay in flight); vmcnt(0) only at tail.
// ---------------------------------------------------------------------------
__global__ __launch_bounds__(512, 4)
void gemm2_mfma(const unsigned short* __restrict__ A,
                const unsigned short* __restrict__ B,
                const int* __restrict__ ids,
                const float* __restrict__ embed,
                float* __restrict__ C)
{
    constexpr int K = D_HID, N = D_MODEL, NKT = K / 64;   // 8 K-tiles
    __shared__ __align__(16) unsigned short lds2[32768];  // 64 KiB
    __shared__ int sIds[128];
    unsigned short* Alds = lds2;            // [2][128][64]
    unsigned short* Blds = lds2 + 16384;

    // bijective XCD-slab swizzle over 2048 blocks (64 row-tiles x 32 col-tiles)
    const int f   = blockIdx.x;
    const int xcd = f & 7;
    const int idx = f >> 3;                         // 0..255
    const int rowBase = (xcd * 8 + (idx & 7)) * 128;
    const int colBase = (idx >> 3) * 128;

    const int tid  = threadIdx.x;
    const int lane = tid & 63;
    const int wv   = tid >> 6;     // 0..7
    const int wr   = wv >> 2;      // 0..1  (M half: 64 rows)
    const int wc   = wv & 3;       // 0..3  (N quarter: 32 cols)
    const int frow = lane & 15;
    const int fq   = lane >> 4;    // 0..3

    if (tid < 128) sIds[tid] = ids[rowBase + tid];

    // stage one 128x64 tile (kt) of A or B into buf kt&1 (2 gloads/thread)
    auto STAGE = [&](const unsigned short* Mp, unsigned short* Ml,
                     int tileBase, int kt) {
        if (kt >= NKT) return;
        unsigned short* Mb = Ml + (kt & 1) * 8192;
        #pragma unroll
        for (int u = 0; u < 2; ++u) {
            const int c    = u * 512 + tid;          // chunk 0..1023
            const int row  = c >> 3;                 // 0..127
            const int slot = (c & 7) ^ (row & 7);    // inverse swizzle on source
            const unsigned short* g = Mp + (size_t)(tileBase + row) * K
                                         + kt * 64 + slot * 8;
            gload_lds16(g, Mb + (u * 512 + wv * 64) * 8);
        }
    };
    auto LDA = [&](int buf, int mf, int kk) -> bf16x8 {
        const int row  = wr * 64 + mf * 16 + frow;
        const int slot = (kk * 4 + fq) ^ (row & 7);
        return *reinterpret_cast<const bf16x8*>(Alds + buf * 8192 + row * 64 + slot * 8);
    };
    auto LDB = [&](int buf, int nf, int kk) -> bf16x8 {
        const int row  = wc * 32 + nf * 16 + frow;
        const int slot = (kk * 4 + fq) ^ (row & 7);
        return *reinterpret_cast<const bf16x8*>(Blds + buf * 8192 + row * 64 + slot * 8);
    };

    f32x4 acc[4][2];
    #pragma unroll
    for (int i = 0; i < 4; i++)
        #pragma unroll
        for (int j = 0; j < 2; j++) acc[i][j] = (f32x4)0.f;

    // prologue: kt0.A, kt0.B, kt1.A (6 vm ops); wait all but kt1.A
    STAGE(A, Alds, rowBase, 0);
    STAGE(B, Blds, colBase, 0);
    STAGE(A, Alds, rowBase, 1);
    asm volatile("s_waitcnt vmcnt(2)" ::: "memory");
    __builtin_amdgcn_s_barrier();
    asm volatile("" ::: "memory");

    #pragma unroll
    for (int kt = 0; kt < NKT; ++kt) {
        const int buf = kt & 1;
        // ---- phase 0 ----
        bf16x8 af0[2][2], bg[2][2];
        #pragma unroll
        for (int i = 0; i < 2; ++i)
            #pragma unroll
            for (int kk = 0; kk < 2; ++kk)
                af0[i][kk] = LDA(buf, i, kk);
        #pragma unroll
        for (int nf = 0; nf < 2; ++nf)
            #pragma unroll
            for (int kk = 0; kk < 2; ++kk)
                bg[nf][kk] = LDB(buf, nf, kk);
        STAGE(B, Blds, colBase, kt + 1);     // -> buf^1.B: race-free
        BAR();
        __builtin_amdgcn_s_setprio(1);
        #pragma unroll
        for (int i = 0; i < 2; ++i)
            #pragma unroll
            for (int nf = 0; nf < 2; ++nf)
                #pragma unroll
                for (int kk = 0; kk < 2; ++kk)
                    acc[i][nf] = __builtin_amdgcn_mfma_f32_16x16x32_bf16(
                        af0[i][kk], bg[nf][kk], acc[i][nf], 0, 0, 0);
        __builtin_amdgcn_s_setprio(0);
        BAR();
        // ---- phase 1 ----
        bf16x8 af1[2][2];
        #pragma unroll
        for (int i = 0; i < 2; ++i)
            #pragma unroll
            for (int kk = 0; kk < 2; ++kk)
                af1[i][kk] = LDA(buf, 2 + i, kk);
        BAR();                               // all waves' buf.A reads complete
        STAGE(A, Alds, rowBase, kt + 2);     // -> buf.A: safe after BAR
        __builtin_amdgcn_s_setprio(1);
        #pragma unroll
        for (int i = 0; i < 2; ++i)
            #pragma unroll
            for (int nf = 0; nf < 2; ++nf)
                #pragma unroll
                for (int kk = 0; kk < 2; ++kk)
                    acc[2 + i][nf] = __builtin_amdgcn_mfma_f32_16x16x32_bf16(
                        af1[i][kk], bg[nf][kk], acc[2 + i][nf], 0, 0, 0);
        __builtin_amdgcn_s_setprio(0);
        if (kt + 2 < NKT)      asm volatile("s_waitcnt vmcnt(2)" ::: "memory");
        else if (kt + 1 < NKT) asm volatile("s_waitcnt vmcnt(0)" ::: "memory");
        BAR();
    }

    // epilogue: embed gather-add + fp32 stores (C/D: row=fq*4+r, col=frow)
    const int ocol0 = colBase + wc * 32 + frow;
    #pragma unroll
    for (int mf = 0; mf < 4; ++mf) {
        #pragma unroll
        for (int r = 0; r < 4; ++r) {
            const int lrow = wr * 64 + mf * 16 + fq * 4 + r;
            const float* e = embed + (size_t)sIds[lrow] * N + ocol0;
            float* o = C + (size_t)(rowBase + lrow) * N + ocol0;
            #pragma unroll
            for (int nf = 0; nf < 2; ++nf)
                o[nf * 16] = acc[mf][nf][r] + e[nf * 16];
        }
    }
}

// ---------------------------------------------------------------------------
// fp32 -> bf16 bulk convert of w1 and w2 in one launch
// ---------------------------------------------------------------------------
__global__ __launch_bounds__(256)
void convert2_bf16(const float* __restrict__ s1, unsigned short* __restrict__ d1, int n1,
                   const float* __restrict__ s2, unsigned short* __restrict__ d2, int n2)
{
    int i = blockIdx.x * 256 + threadIdx.x;
    const float* src; unsigned short* dst;
    if (i < n1) { src = s1; dst = d1; }
    else {
        i -= n1;
        if (i >= n2) return;
        src = s2; dst = d2;
    }
    const float4 v = reinterpret_cast<const float4*>(src)[i];
    ushort4 o;
    o.x = f2bf(v.x); o.y = f2bf(v.y); o.z = f2bf(v.z); o.w = f2bf(v.w);
    reinterpret_cast<ushort4*>(dst)[i] = o;
}

// ---------------------------------------------------------------------------
// In-place LayerNorm + ELU on bf16 H [TOKENS][512]. One wave per row.
// ---------------------------------------------------------------------------
__global__ __launch_bounds__(256)
void ln_elu_bf16(unsigned short* __restrict__ H,
                 const float* __restrict__ ln_w, const float* __restrict__ ln_b)
{
    const int row = blockIdx.x * 4 + (threadIdx.x >> 6);
    const int t = threadIdx.x & 63;
    unsigned short* x = H + (size_t)row * D_HID + t * 8;

    bf16x8 v = *reinterpret_cast<const bf16x8*>(x);
    float fv[8], s = 0.f, ss = 0.f;
    #pragma unroll
    for (int j = 0; j < 8; j++) {
        fv[j] = bf2f((unsigned short)v[j]);
        s += fv[j]; ss += fv[j] * fv[j];
    }
    #pragma unroll
    for (int off = 32; off > 0; off >>= 1) {
        s  += __shfl_down(s, off);
        ss += __shfl_down(ss, off);
    }
    s = __shfl(s, 0); ss = __shfl(ss, 0);
    const float mu = s * (1.f / D_HID);
    const float var = ss * (1.f / D_HID) - mu * mu;
    const float rstd = rsqrtf(var + 1e-5f);

    const float4 w0 = *reinterpret_cast<const float4*>(ln_w + t * 8);
    const float4 w1 = *reinterpret_cast<const float4*>(ln_w + t * 8 + 4);
    const float4 b0 = *reinterpret_cast<const float4*>(ln_b + t * 8);
    const float4 b1 = *reinterpret_cast<const float4*>(ln_b + t * 8 + 4);
    const float wa[8] = { w0.x, w0.y, w0.z, w0.w, w1.x, w1.y, w1.z, w1.w };
    const float ba[8] = { b0.x, b0.y, b0.z, b0.w, b1.x, b1.y, b1.z, b1.w };

    bf16x8 o;
    #pragma unroll
    for (int j = 0; j < 8; j++) {
        float y = (fv[j] - mu) * rstd * wa[j] + ba[j];
        y = y > 0.f ? y : expm1f(y);
        o[j] = (short)f2bf(y);
    }
    *reinterpret_cast<bf16x8*>(x) = o;
}

extern "C" void kernel_launch(void* const* d_in, const int* in_sizes, int n_in,
                              void* d_out, int out_size, void* d_ws, size_t ws_size,
                              hipStream_t stream)
{
    const float* real  = (const float*)d_in[0];   // [32000, 768]
    const float* embed = (const float*)d_in[1];   // [32000, 4096]
    const float* w1    = (const float*)d_in[2];   // [512, 768]
    const float* w2    = (const float*)d_in[3];   // [4096, 512]
    const float* ln_w  = (const float*)d_in[4];   // [512]
    const float* ln_b  = (const float*)d_in[5];   // [512]
    const int*   ids   = (const int*)d_in[6];     // [8192]
    float* out = (float*)d_out;                   // [8192, 4096] fp32

    unsigned short* Hb  = (unsigned short*)d_ws;             // [8192][512] bf16
    unsigned short* w1b = Hb  + (size_t)TOKENS * D_HID;      // [512][768]  bf16
    unsigned short* w2b = w1b + (size_t)D_HID * D_REAL;      // [4096][512] bf16

    const int n1 = D_HID * D_REAL / 4, n2 = D_MODEL * D_HID / 4;
    convert2_bf16<<<(n1 + n2 + 255) / 256, 256, 0, stream>>>(w1, w1b, n1, w2, w2b, n2);

    dim3 g1(TOKENS / 64, D_HID / 128);
    gemm1_mfma<<<g1, 256, 0, stream>>>(real, ids, w1b, Hb);

    ln_elu_bf16<<<TOKENS / 4, 256, 0, stream>>>(Hb, ln_w, ln_b);

    gemm2_mfma<<<2048, 512, 0, stream>>>(Hb, w2b, ids, embed, out);
}